// Round 3
// baseline (790.527 us; speedup 1.0000x reference)
//
#include <hip/hip_runtime.h>
#include <math.h>

#define LD    512
#define CB    1024
#define NTOK  65536
#define HALFM 32768

typedef unsigned short u16;
typedef __attribute__((ext_vector_type(8))) short bf16x8;   // 8 bf16 (4 VGPRs)
typedef __attribute__((ext_vector_type(4))) float f32x4;

#define GLAS  __attribute__((address_space(1)))
#define LDSAS __attribute__((address_space(3)))

__device__ inline void glds16(const void* g, void* l) {
    __builtin_amdgcn_global_load_lds((const GLAS unsigned int*)g,
                                     (LDSAS unsigned int*)l, 16, 0, 0);
}

__device__ inline u16 f2bf_rne(float f) {
    union { float f; unsigned u; } v; v.f = f;
    unsigned u = v.u;
    return (u16)((u + 0x7fffu + ((u >> 16) & 1u)) >> 16);
}
__device__ inline float bf2f(u16 h) {
    union { unsigned u; float f; } v; v.u = ((unsigned)h) << 16;
    return v.f;
}

// ---------------------------------------------------------------------------
// best[] initializer (device-side; no host runtime calls in kernel_launch).
// ---------------------------------------------------------------------------
__global__ __launch_bounds__(256)
void init_best_kernel(unsigned long long* __restrict__ best, int n) {
    int i = blockIdx.x * blockDim.x + threadIdx.x;
    if (i < n) best[i] = 0xFFFFFFFFFFFFFFFFull;
}

// ---------------------------------------------------------------------------
// Converter: per row (one wave): hi = bf16(x), lo = bf16(x - hi), sumsq(x).
// ---------------------------------------------------------------------------
__global__ __launch_bounds__(256)
void convert_rows_kernel(const float* __restrict__ src,
                         u16* __restrict__ hi,
                         u16* __restrict__ lo,
                         float* __restrict__ sumsq,
                         int nrows) {
    int wave = (int)((blockIdx.x * blockDim.x + threadIdx.x) >> 6);
    int lane = threadIdx.x & 63;
    if (wave >= nrows) return;
    const float4* p = (const float4*)(src + (size_t)wave * LD);
    float s = 0.f;
    #pragma unroll
    for (int c = 0; c < 2; ++c) {
        float4 v = p[lane + c * 64];
        float fs[4] = {v.x, v.y, v.z, v.w};
        ushort4 hv, lv;
        u16 hh[4], ll[4];
        #pragma unroll
        for (int e = 0; e < 4; ++e) {
            s += fs[e] * fs[e];
            u16 hb = f2bf_rne(fs[e]);
            float hf = bf2f(hb);
            hh[e] = hb;
            ll[e] = f2bf_rne(fs[e] - hf);
        }
        hv.x = hh[0]; hv.y = hh[1]; hv.z = hh[2]; hv.w = hh[3];
        lv.x = ll[0]; lv.y = ll[1]; lv.z = ll[2]; lv.w = ll[3];
        size_t off = (size_t)wave * LD + (size_t)(lane + c * 64) * 4;
        *(ushort4*)(hi + off) = hv;
        *(ushort4*)(lo + off) = lv;
    }
    #pragma unroll
    for (int off = 32; off > 0; off >>= 1) s += __shfl_down(s, off, 64);
    if (lane == 0) sumsq[wave] = s;
}

// ---------------------------------------------------------------------------
// Fused MFMA distance GEMM:
//   dist[m][n] = a2[m] - 2*(AhiBhi + AloBhi + AhiBlo) + b2[n]
// One K-loop stages Ahi/Alo/Bhi/Blo per BK=32 chunk (32KB LDS) and issues
// 48 MFMAs per barrier-pair. Row stride 64B = 8-way LDS floor.
// XCD swizzle: 2048 blocks % 8 == 0 -> bijective (id%8)*256 + id/8 remap so
// each XCD owns 32 contiguous M-panels x all 8 N-blocks (A-panel fetched
// into exactly one L2 instead of eight).
// Epilogue folds per-row argmin into a u64 atomicMin when best != nullptr.
// ---------------------------------------------------------------------------
__global__ __launch_bounds__(256)
void mfma_dist_fused_kernel(const u16* __restrict__ Ahi,
                            const u16* __restrict__ Alo,
                            const u16* __restrict__ Bhi,
                            const u16* __restrict__ Blo,
                            const float* __restrict__ a2,   // full array
                            const float* __restrict__ b2,
                            float* __restrict__ dist,       // full base
                            int m_base,
                            unsigned long long* __restrict__ best) {
    __shared__ u16 AsH[128 * 32];   // row-major: row m (64B), k contiguous
    __shared__ u16 AsL[128 * 32];
    __shared__ u16 BsH[128 * 32];
    __shared__ u16 BsL[128 * 32];

    const int tid  = threadIdx.x;
    const int lane = tid & 63;
    const int w    = tid >> 6;        // wave 0..3
    const int wm   = w >> 1;          // 2x2 wave grid
    const int wn   = w & 1;
    const int quad = lane >> 4;
    const int l15  = lane & 15;

    // XCD-aware swizzle (gridDim = (8, 256), nwg = 2048, nwg % 8 == 0)
    const int id   = blockIdx.y * gridDim.x + blockIdx.x;   // dispatch order
    const int cpx  = (gridDim.x * gridDim.y) >> 3;          // 256 per XCD
    const int sid  = (id & 7) * cpx + (id >> 3);            // bijective
    const int bn   = sid & 7;                               // N-block 0..7
    const int bm   = sid >> 3;                              // M-panel 0..255

    const int n0 = bn * 128;
    const int m0 = bm * 128;          // local (phase) row

    f32x4 acc[4][4];
    #pragma unroll
    for (int i = 0; i < 4; ++i)
        #pragma unroll
        for (int j = 0; j < 4; ++j) {
            f32x4 z = {0.f, 0.f, 0.f, 0.f};
            acc[i][j] = z;
        }

    const int srow = lane >> 2;        // 0..15 (16 rows per glds16)
    const int scol = (lane & 3) * 8;   // element offset within 32-wide k

    #pragma unroll 1
    for (int k0 = 0; k0 < LD; k0 += 32) {
        // stage 128x32 tiles of Ahi/Alo/Bhi/Blo: 8 glds16 per wave
        #pragma unroll
        for (int t = 0; t < 2; ++t) {
            int rb = w * 32 + t * 16;       // wave-uniform row base
            int r  = rb + srow;
            size_t offA = (size_t)(m0 + r) * LD + k0 + scol;
            size_t offB = (size_t)(n0 + r) * LD + k0 + scol;
            glds16(Ahi + offA, AsH + rb * 32);
            glds16(Alo + offA, AsL + rb * 32);
            glds16(Bhi + offB, BsH + rb * 32);
            glds16(Blo + offB, BsL + rb * 32);
        }
        __syncthreads();   // drains vmcnt (glds) before consume

        bf16x8 ah[4], bh[4], al[4], bl[4];
        #pragma unroll
        for (int i = 0; i < 4; ++i)
            ah[i] = *(const bf16x8*)&AsH[(wm * 64 + i * 16 + l15) * 32 + quad * 8];
        #pragma unroll
        for (int j = 0; j < 4; ++j)
            bh[j] = *(const bf16x8*)&BsH[(wn * 64 + j * 16 + l15) * 32 + quad * 8];
        #pragma unroll
        for (int i = 0; i < 4; ++i)
            #pragma unroll
            for (int j = 0; j < 4; ++j)
                acc[i][j] = __builtin_amdgcn_mfma_f32_16x16x32_bf16(
                    ah[i], bh[j], acc[i][j], 0, 0, 0);
        #pragma unroll
        for (int i = 0; i < 4; ++i)
            al[i] = *(const bf16x8*)&AsL[(wm * 64 + i * 16 + l15) * 32 + quad * 8];
        #pragma unroll
        for (int i = 0; i < 4; ++i)
            #pragma unroll
            for (int j = 0; j < 4; ++j)
                acc[i][j] = __builtin_amdgcn_mfma_f32_16x16x32_bf16(
                    al[i], bh[j], acc[i][j], 0, 0, 0);
        #pragma unroll
        for (int j = 0; j < 4; ++j)
            bl[j] = *(const bf16x8*)&BsL[(wn * 64 + j * 16 + l15) * 32 + quad * 8];
        #pragma unroll
        for (int i = 0; i < 4; ++i)
            #pragma unroll
            for (int j = 0; j < 4; ++j)
                acc[i][j] = __builtin_amdgcn_mfma_f32_16x16x32_bf16(
                    ah[i], bl[j], acc[i][j], 0, 0, 0);
        __syncthreads();   // protect LDS before next stage overwrite
    }

    // epilogue: C/D layout col = lane&15, row = quad*4 + reg
    #pragma unroll
    for (int i = 0; i < 4; ++i) {
        const int rowb = m_base + m0 + wm * 64 + i * 16 + quad * 4;  // +r
        float a2v[4];
        #pragma unroll
        for (int r = 0; r < 4; ++r) a2v[r] = a2[rowb + r];
        float bval[4]; int bcol[4];
        #pragma unroll
        for (int r = 0; r < 4; ++r) { bval[r] = INFINITY; bcol[r] = 0; }
        #pragma unroll
        for (int j = 0; j < 4; ++j) {
            int col = n0 + wn * 64 + j * 16 + l15;
            float b2v = b2[col];
            #pragma unroll
            for (int r = 0; r < 4; ++r) {
                float d = fmaf(-2.f, acc[i][j][r], a2v[r] + b2v);
                dist[(size_t)(rowb + r) * CB + col] = d;
                if (d < bval[r]) { bval[r] = d; bcol[r] = col; }
            }
        }
        if (best) {
            // reduce across the 16 lanes of this quad group (64-col slice)
            #pragma unroll
            for (int off = 8; off > 0; off >>= 1) {
                #pragma unroll
                for (int r = 0; r < 4; ++r) {
                    float ov = __shfl_xor(bval[r], off, 64);
                    int   oc = __shfl_xor(bcol[r], off, 64);
                    if (ov < bval[r] || (ov == bval[r] && oc < bcol[r])) {
                        bval[r] = ov; bcol[r] = oc;
                    }
                }
            }
            if (l15 == 0) {
                #pragma unroll
                for (int r = 0; r < 4; ++r) {
                    unsigned fb = __float_as_uint(bval[r]);
                    fb = (fb & 0x80000000u) ? ~fb : (fb | 0x80000000u);
                    unsigned long long key =
                        ((unsigned long long)fb << 32) | (unsigned)bcol[r];
                    atomicMin(best + rowb + r, key);
                }
            }
        }
    }
}

// ---------------------------------------------------------------------------
// K3 fallback: per-token argmin (np first-occurrence tie-break) + gather.
// Used only when d_ws is too small for the fused-argmin fast path.
// ---------------------------------------------------------------------------
__global__ __launch_bounds__(256)
void argmin_gather_kernel(const float* __restrict__ dist,
                          const float* __restrict__ cb,
                          float* __restrict__ quant) {
    int wave = (int)((blockIdx.x * blockDim.x + threadIdx.x) >> 6);
    int lane = threadIdx.x & 63;
    if (wave >= NTOK) return;

    const float4* dp = (const float4*)(dist + (size_t)wave * CB);
    float best = INFINITY;
    int bidx = 0x7fffffff;
    #pragma unroll
    for (int i = 0; i < 4; ++i) {
        float4 v = dp[i * 64 + lane];
        int base = (i * 64 + lane) * 4;
        if (v.x < best) { best = v.x; bidx = base + 0; }
        if (v.y < best) { best = v.y; bidx = base + 1; }
        if (v.z < best) { best = v.z; bidx = base + 2; }
        if (v.w < best) { best = v.w; bidx = base + 3; }
    }
    #pragma unroll
    for (int off = 32; off > 0; off >>= 1) {
        float ov = __shfl_down(best, off, 64);
        int   oi = __shfl_down(bidx, off, 64);
        if (ov < best || (ov == best && oi < bidx)) { best = ov; bidx = oi; }
    }
    bidx = __shfl(bidx, 0, 64);

    const float4* cp = (const float4*)(cb + (size_t)bidx * LD);
    float4* qp = (float4*)(quant + (size_t)wave * LD);
    qp[lane]      = cp[lane];
    qp[lane + 64] = cp[lane + 64];
}

// ---------------------------------------------------------------------------
// K3 fast path: argmin already reduced into best[] by the GEMM epilogue;
// just decode the index and gather the codebook row.
// ---------------------------------------------------------------------------
__global__ __launch_bounds__(256)
void gather_fast_kernel(const unsigned long long* __restrict__ best,
                        const float* __restrict__ cb,
                        float* __restrict__ quant) {
    int wave = (int)((blockIdx.x * blockDim.x + threadIdx.x) >> 6);
    int lane = threadIdx.x & 63;
    if (wave >= NTOK) return;

    int bidx = (int)(best[wave] & 0xffffffffull);

    const float4* cp = (const float4*)(cb + (size_t)bidx * LD);
    float4* qp = (float4*)(quant + (size_t)wave * LD);
    qp[lane]      = cp[lane];
    qp[lane + 64] = cp[lane + 64];
}

// ---------------------------------------------------------------------------
// Memory plan inside d_out (d_ws only for the 512KB best[] table, gated):
//   quant region Q   = d_out[0 .. 134,217,728)
//     cb_hi @0 (1MB), cb_lo @1MB, b2 @2MB (4KB), a2 @2MB+4KB (256KB),
//     phase-B Ahi @4MB (32MB), phase-B Alo @4MB+32MB
//   dist region D    = d_out[134,217,728 .. 402,653,184)
//     phase-A Ahi/Alo live in D's SECOND half while gemm-A writes D's first
//     half; gemm-B then overwrites D's second half (phase-A data dead).
//   best[] (NTOK u64 = 512KB) lives in d_ws iff ws_size permits; otherwise
//   fall back to the dist-reading argmin kernel.
//   K3 runs last and overwrites Q with the real quantized output.
// ---------------------------------------------------------------------------
extern "C" void kernel_launch(void* const* d_in, const int* in_sizes, int n_in,
                              void* d_out, int out_size, void* d_ws, size_t ws_size,
                              hipStream_t stream) {
    const float* x  = (const float*)d_in[0];
    const float* cb = (const float*)d_in[1];

    char* out = (char*)d_out;
    const size_t QBYTES = (size_t)NTOK * LD * 4;     // 134,217,728
    float* quant = (float*)out;
    float* dist  = (float*)(out + QBYTES);

    u16*   cbhi = (u16*)out;
    u16*   cblo = (u16*)(out + 1048576);
    float* b2   = (float*)(out + 2097152);
    float* a2   = (float*)(out + 2101248);
    u16*   A2hi = (u16*)(out + 4194304);
    u16*   A2lo = (u16*)(out + 4194304 + 33554432);

    char*  db   = out + QBYTES;
    u16*   A1hi = (u16*)(db + 134217728);
    u16*   A1lo = (u16*)(db + 134217728 + 33554432);

    const bool fuse_argmin = (d_ws != nullptr) &&
                             (ws_size >= (size_t)NTOK * 8);
    unsigned long long* best = (unsigned long long*)d_ws;
    if (fuse_argmin)
        init_best_kernel<<<NTOK / 256, 256, 0, stream>>>(best, NTOK);

    // converters
    convert_rows_kernel<<<CB / 4, 256, 0, stream>>>(cb, cbhi, cblo, b2, CB);
    convert_rows_kernel<<<HALFM / 4, 256, 0, stream>>>(x, A1hi, A1lo, a2, HALFM);
    convert_rows_kernel<<<HALFM / 4, 256, 0, stream>>>(
        x + (size_t)HALFM * LD, A2hi, A2lo, a2 + HALFM, HALFM);

    // fused distance GEMMs (two M-phases)
    dim3 grid(CB / 128, HALFM / 128);
    mfma_dist_fused_kernel<<<grid, 256, 0, stream>>>(
        A1hi, A1lo, cbhi, cblo, a2, b2, dist, 0,
        fuse_argmin ? best : nullptr);
    mfma_dist_fused_kernel<<<grid, 256, 0, stream>>>(
        A2hi, A2lo, cbhi, cblo, a2, b2, dist, HALFM,
        fuse_argmin ? best : nullptr);

    // argmin + gather (overwrites scratch in Q with the real output)
    if (fuse_argmin)
        gather_fast_kernel<<<NTOK / 4, 256, 0, stream>>>(best, cb, quant);
    else
        argmin_gather_kernel<<<NTOK / 4, 256, 0, stream>>>(dist, cb, quant);
}

// Round 4
// 774.172 us; speedup vs baseline: 1.0211x; 1.0211x over previous
//
#include <hip/hip_runtime.h>
#include <math.h>

#define LD    512
#define CB    1024
#define NTOK  65536
#define HALFM 32768

typedef unsigned short u16;
typedef __attribute__((ext_vector_type(8))) short bf16x8;   // 8 bf16 (4 VGPRs)
typedef __attribute__((ext_vector_type(4))) float f32x4;

#define GLAS  __attribute__((address_space(1)))
#define LDSAS __attribute__((address_space(3)))

__device__ inline void glds16(const void* g, void* l) {
    __builtin_amdgcn_global_load_lds((const GLAS unsigned int*)g,
                                     (LDSAS unsigned int*)l, 16, 0, 0);
}

__device__ inline u16 f2bf_rne(float f) {
    union { float f; unsigned u; } v; v.f = f;
    unsigned u = v.u;
    return (u16)((u + 0x7fffu + ((u >> 16) & 1u)) >> 16);
}
__device__ inline float bf2f(u16 h) {
    union { unsigned u; float f; } v; v.u = ((unsigned)h) << 16;
    return v.f;
}

// ---------------------------------------------------------------------------
// best[] initializer (device-side; no host runtime calls in kernel_launch).
// ---------------------------------------------------------------------------
__global__ __launch_bounds__(256)
void init_best_kernel(unsigned long long* __restrict__ best, int n) {
    int i = blockIdx.x * blockDim.x + threadIdx.x;
    if (i < n) best[i] = 0xFFFFFFFFFFFFFFFFull;
}

// ---------------------------------------------------------------------------
// Converter: per row (one wave): hi = bf16(x), lo = bf16(x - hi), sumsq(x).
// ---------------------------------------------------------------------------
__global__ __launch_bounds__(256)
void convert_rows_kernel(const float* __restrict__ src,
                         u16* __restrict__ hi,
                         u16* __restrict__ lo,
                         float* __restrict__ sumsq,
                         int nrows) {
    int wave = (int)((blockIdx.x * blockDim.x + threadIdx.x) >> 6);
    int lane = threadIdx.x & 63;
    if (wave >= nrows) return;
    const float4* p = (const float4*)(src + (size_t)wave * LD);
    float s = 0.f;
    #pragma unroll
    for (int c = 0; c < 2; ++c) {
        float4 v = p[lane + c * 64];
        float fs[4] = {v.x, v.y, v.z, v.w};
        ushort4 hv, lv;
        u16 hh[4], ll[4];
        #pragma unroll
        for (int e = 0; e < 4; ++e) {
            s += fs[e] * fs[e];
            u16 hb = f2bf_rne(fs[e]);
            float hf = bf2f(hb);
            hh[e] = hb;
            ll[e] = f2bf_rne(fs[e] - hf);
        }
        hv.x = hh[0]; hv.y = hh[1]; hv.z = hh[2]; hv.w = hh[3];
        lv.x = ll[0]; lv.y = ll[1]; lv.z = ll[2]; lv.w = ll[3];
        size_t off = (size_t)wave * LD + (size_t)(lane + c * 64) * 4;
        *(ushort4*)(hi + off) = hv;
        *(ushort4*)(lo + off) = lv;
    }
    #pragma unroll
    for (int off = 32; off > 0; off >>= 1) s += __shfl_down(s, off, 64);
    if (lane == 0) sumsq[wave] = s;
}

// ---------------------------------------------------------------------------
// Fused MFMA distance GEMM, 2-phase double-buffered K-loop:
//   dist[m][n] = a2[m] - 2*(AhiBhi + AloBhi + AhiBlo) + b2[n]
// Per K-iter: STAGE(next buf) -> ds_read(cur) + 48 MFMA -> __syncthreads().
// One barrier per iter; glds16 latency hides under current-tile compute.
// __syncthreads()'s implicit vmcnt(0) is exactly the stage-completion wait.
// LDS 2x(4x8KB)=64KB -> 2 blocks/CU. XCD swizzle: bijective (2048%8==0).
// Epilogue folds per-row argmin into a u64 atomicMin when best != nullptr;
// dist written nontemporal (write-once stream, keeps codebook L2-resident).
// ---------------------------------------------------------------------------
__global__ __launch_bounds__(256, 2)
void mfma_dist_fused_kernel(const u16* __restrict__ Ahi,
                            const u16* __restrict__ Alo,
                            const u16* __restrict__ Bhi,
                            const u16* __restrict__ Blo,
                            const float* __restrict__ a2,   // full array
                            const float* __restrict__ b2,
                            float* __restrict__ dist,       // full base
                            int m_base,
                            unsigned long long* __restrict__ best) {
    __shared__ u16 AsH[2][128 * 32];   // row-major: row m (64B), k contiguous
    __shared__ u16 AsL[2][128 * 32];
    __shared__ u16 BsH[2][128 * 32];
    __shared__ u16 BsL[2][128 * 32];

    const int tid  = threadIdx.x;
    const int lane = tid & 63;
    const int w    = tid >> 6;        // wave 0..3
    const int wm   = w >> 1;          // 2x2 wave grid
    const int wn   = w & 1;
    const int quad = lane >> 4;
    const int l15  = lane & 15;

    // XCD-aware swizzle (gridDim = (8, 256), nwg = 2048, nwg % 8 == 0)
    const int id   = blockIdx.y * gridDim.x + blockIdx.x;   // dispatch order
    const int cpx  = (gridDim.x * gridDim.y) >> 3;          // 256 per XCD
    const int sid  = (id & 7) * cpx + (id >> 3);            // bijective
    const int bn   = sid & 7;                               // N-block 0..7
    const int bm   = sid >> 3;                              // M-panel 0..255

    const int n0 = bn * 128;
    const int m0 = bm * 128;          // local (phase) row

    f32x4 acc[4][4];
    #pragma unroll
    for (int i = 0; i < 4; ++i)
        #pragma unroll
        for (int j = 0; j < 4; ++j) {
            f32x4 z = {0.f, 0.f, 0.f, 0.f};
            acc[i][j] = z;
        }

    const int srow = lane >> 2;        // 0..15 (16 rows per glds16)
    const int scol = (lane & 3) * 8;   // element offset within 32-wide k

#define STAGE(B, K0) do {                                                   \
        _Pragma("unroll")                                                   \
        for (int t = 0; t < 2; ++t) {                                       \
            const int rb = w * 32 + t * 16;   /* wave-uniform LDS base */   \
            const int r  = rb + srow;                                       \
            size_t offA = (size_t)(m0 + r) * LD + (K0) + scol;              \
            size_t offB = (size_t)(n0 + r) * LD + (K0) + scol;              \
            glds16(Ahi + offA, &AsH[B][rb * 32]);                           \
            glds16(Alo + offA, &AsL[B][rb * 32]);                           \
            glds16(Bhi + offB, &BsH[B][rb * 32]);                           \
            glds16(Blo + offB, &BsL[B][rb * 32]);                           \
        }                                                                   \
    } while (0)

#define COMPUTE(B) do {                                                     \
        bf16x8 ah[4], bh[4], xf[4];                                         \
        _Pragma("unroll")                                                   \
        for (int i = 0; i < 4; ++i)                                         \
            ah[i] = *(const bf16x8*)&AsH[B][(wm * 64 + i * 16 + l15) * 32 + quad * 8]; \
        _Pragma("unroll")                                                   \
        for (int j = 0; j < 4; ++j)                                         \
            bh[j] = *(const bf16x8*)&BsH[B][(wn * 64 + j * 16 + l15) * 32 + quad * 8]; \
        _Pragma("unroll")                                                   \
        for (int i = 0; i < 4; ++i)                                         \
            _Pragma("unroll")                                               \
            for (int j = 0; j < 4; ++j)                                     \
                acc[i][j] = __builtin_amdgcn_mfma_f32_16x16x32_bf16(        \
                    ah[i], bh[j], acc[i][j], 0, 0, 0);                      \
        _Pragma("unroll")                                                   \
        for (int i = 0; i < 4; ++i)                                         \
            xf[i] = *(const bf16x8*)&AsL[B][(wm * 64 + i * 16 + l15) * 32 + quad * 8]; \
        _Pragma("unroll")                                                   \
        for (int i = 0; i < 4; ++i)                                         \
            _Pragma("unroll")                                               \
            for (int j = 0; j < 4; ++j)                                     \
                acc[i][j] = __builtin_amdgcn_mfma_f32_16x16x32_bf16(        \
                    xf[i], bh[j], acc[i][j], 0, 0, 0);                      \
        _Pragma("unroll")                                                   \
        for (int j = 0; j < 4; ++j)                                         \
            xf[j] = *(const bf16x8*)&BsL[B][(wn * 64 + j * 16 + l15) * 32 + quad * 8]; \
        _Pragma("unroll")                                                   \
        for (int i = 0; i < 4; ++i)                                         \
            _Pragma("unroll")                                               \
            for (int j = 0; j < 4; ++j)                                     \
                acc[i][j] = __builtin_amdgcn_mfma_f32_16x16x32_bf16(        \
                    ah[i], xf[j], acc[i][j], 0, 0, 0);                      \
    } while (0)

    // prologue: fill buffer 0 for k0 = 0
    STAGE(0, 0);
    __syncthreads();

    // 16 K-steps, 2 per trip (static buffer indices)
    #pragma unroll 1
    for (int tp = 0; tp < 8; ++tp) {
        const int k0 = tp * 64;
        STAGE(1, k0 + 32);          // issue next-tile loads first
        COMPUTE(0);                 // compute current (compiler inserts lgkm waits)
        __syncthreads();            // vmcnt(0)+lgkmcnt(0)+barrier: buf1 ready
        if (tp < 7) STAGE(0, k0 + 64);
        COMPUTE(1);
        __syncthreads();
    }
#undef STAGE
#undef COMPUTE

    // epilogue: C/D layout col = lane&15, row = quad*4 + reg
    #pragma unroll
    for (int i = 0; i < 4; ++i) {
        const int rowb = m_base + m0 + wm * 64 + i * 16 + quad * 4;  // +r
        float a2v[4];
        #pragma unroll
        for (int r = 0; r < 4; ++r) a2v[r] = a2[rowb + r];
        float bval[4]; int bcol[4];
        #pragma unroll
        for (int r = 0; r < 4; ++r) { bval[r] = INFINITY; bcol[r] = 0; }
        #pragma unroll
        for (int j = 0; j < 4; ++j) {
            int col = n0 + wn * 64 + j * 16 + l15;
            float b2v = b2[col];
            #pragma unroll
            for (int r = 0; r < 4; ++r) {
                float d = fmaf(-2.f, acc[i][j][r], a2v[r] + b2v);
                __builtin_nontemporal_store(d, &dist[(size_t)(rowb + r) * CB + col]);
                if (d < bval[r]) { bval[r] = d; bcol[r] = col; }
            }
        }
        if (best) {
            // reduce across the 16 lanes of this quad group (64-col slice)
            #pragma unroll
            for (int off = 8; off > 0; off >>= 1) {
                #pragma unroll
                for (int r = 0; r < 4; ++r) {
                    float ov = __shfl_xor(bval[r], off, 64);
                    int   oc = __shfl_xor(bcol[r], off, 64);
                    if (ov < bval[r] || (ov == bval[r] && oc < bcol[r])) {
                        bval[r] = ov; bcol[r] = oc;
                    }
                }
            }
            if (l15 == 0) {
                #pragma unroll
                for (int r = 0; r < 4; ++r) {
                    unsigned fb = __float_as_uint(bval[r]);
                    fb = (fb & 0x80000000u) ? ~fb : (fb | 0x80000000u);
                    unsigned long long key =
                        ((unsigned long long)fb << 32) | (unsigned)bcol[r];
                    atomicMin(best + rowb + r, key);
                }
            }
        }
    }
}

// ---------------------------------------------------------------------------
// K3 fallback: per-token argmin (np first-occurrence tie-break) + gather.
// Used only when d_ws is too small for the fused-argmin fast path.
// ---------------------------------------------------------------------------
__global__ __launch_bounds__(256)
void argmin_gather_kernel(const float* __restrict__ dist,
                          const float* __restrict__ cb,
                          float* __restrict__ quant) {
    int wave = (int)((blockIdx.x * blockDim.x + threadIdx.x) >> 6);
    int lane = threadIdx.x & 63;
    if (wave >= NTOK) return;

    const float4* dp = (const float4*)(dist + (size_t)wave * CB);
    float best = INFINITY;
    int bidx = 0x7fffffff;
    #pragma unroll
    for (int i = 0; i < 4; ++i) {
        float4 v = dp[i * 64 + lane];
        int base = (i * 64 + lane) * 4;
        if (v.x < best) { best = v.x; bidx = base + 0; }
        if (v.y < best) { best = v.y; bidx = base + 1; }
        if (v.z < best) { best = v.z; bidx = base + 2; }
        if (v.w < best) { best = v.w; bidx = base + 3; }
    }
    #pragma unroll
    for (int off = 32; off > 0; off >>= 1) {
        float ov = __shfl_down(best, off, 64);
        int   oi = __shfl_down(bidx, off, 64);
        if (ov < best || (ov == best && oi < bidx)) { best = ov; bidx = oi; }
    }
    bidx = __shfl(bidx, 0, 64);

    const float4* cp = (const float4*)(cb + (size_t)bidx * LD);
    float4* qp = (float4*)(quant + (size_t)wave * LD);
    qp[lane]      = cp[lane];
    qp[lane + 64] = cp[lane + 64];
}

// ---------------------------------------------------------------------------
// K3 fast path: argmin already reduced into best[] by the GEMM epilogue;
// just decode the index and gather the codebook row.
// ---------------------------------------------------------------------------
__global__ __launch_bounds__(256)
void gather_fast_kernel(const unsigned long long* __restrict__ best,
                        const float* __restrict__ cb,
                        float* __restrict__ quant) {
    int wave = (int)((blockIdx.x * blockDim.x + threadIdx.x) >> 6);
    int lane = threadIdx.x & 63;
    if (wave >= NTOK) return;

    int bidx = (int)(best[wave] & 0xffffffffull);

    const float4* cp = (const float4*)(cb + (size_t)bidx * LD);
    float4* qp = (float4*)(quant + (size_t)wave * LD);
    qp[lane]      = cp[lane];
    qp[lane + 64] = cp[lane + 64];
}

// ---------------------------------------------------------------------------
// Memory plan inside d_out (d_ws only for the 512KB best[] table, gated):
//   quant region Q   = d_out[0 .. 134,217,728)
//     cb_hi @0 (1MB), cb_lo @1MB, b2 @2MB (4KB), a2 @2MB+4KB (256KB),
//     phase-B Ahi @4MB (32MB), phase-B Alo @4MB+32MB
//   dist region D    = d_out[134,217,728 .. 402,653,184)
//     phase-A Ahi/Alo live in D's SECOND half while gemm-A writes D's first
//     half; gemm-B then overwrites D's second half (phase-A data dead).
//   best[] (NTOK u64 = 512KB) lives in d_ws iff ws_size permits; otherwise
//   fall back to the dist-reading argmin kernel.
//   K3 runs last and overwrites Q with the real quantized output.
// ---------------------------------------------------------------------------
extern "C" void kernel_launch(void* const* d_in, const int* in_sizes, int n_in,
                              void* d_out, int out_size, void* d_ws, size_t ws_size,
                              hipStream_t stream) {
    const float* x  = (const float*)d_in[0];
    const float* cb = (const float*)d_in[1];

    char* out = (char*)d_out;
    const size_t QBYTES = (size_t)NTOK * LD * 4;     // 134,217,728
    float* quant = (float*)out;
    float* dist  = (float*)(out + QBYTES);

    u16*   cbhi = (u16*)out;
    u16*   cblo = (u16*)(out + 1048576);
    float* b2   = (float*)(out + 2097152);
    float* a2   = (float*)(out + 2101248);
    u16*   A2hi = (u16*)(out + 4194304);
    u16*   A2lo = (u16*)(out + 4194304 + 33554432);

    char*  db   = out + QBYTES;
    u16*   A1hi = (u16*)(db + 134217728);
    u16*   A1lo = (u16*)(db + 134217728 + 33554432);

    const bool fuse_argmin = (d_ws != nullptr) &&
                             (ws_size >= (size_t)NTOK * 8);
    unsigned long long* best = (unsigned long long*)d_ws;
    if (fuse_argmin)
        init_best_kernel<<<NTOK / 256, 256, 0, stream>>>(best, NTOK);

    // converters
    convert_rows_kernel<<<CB / 4, 256, 0, stream>>>(cb, cbhi, cblo, b2, CB);
    convert_rows_kernel<<<HALFM / 4, 256, 0, stream>>>(x, A1hi, A1lo, a2, HALFM);
    convert_rows_kernel<<<HALFM / 4, 256, 0, stream>>>(
        x + (size_t)HALFM * LD, A2hi, A2lo, a2 + HALFM, HALFM);

    // fused distance GEMMs (two M-phases)
    dim3 grid(CB / 128, HALFM / 128);
    mfma_dist_fused_kernel<<<grid, 256, 0, stream>>>(
        A1hi, A1lo, cbhi, cblo, a2, b2, dist, 0,
        fuse_argmin ? best : nullptr);
    mfma_dist_fused_kernel<<<grid, 256, 0, stream>>>(
        A2hi, A2lo, cbhi, cblo, a2, b2, dist, HALFM,
        fuse_argmin ? best : nullptr);

    // argmin + gather (overwrites scratch in Q with the real output)
    if (fuse_argmin)
        gather_fast_kernel<<<NTOK / 4, 256, 0, stream>>>(best, cb, quant);
    else
        argmin_gather_kernel<<<NTOK / 4, 256, 0, stream>>>(dist, cb, quant);
}